// Round 1
// baseline (47431.699 us; speedup 1.0000x reference)
//
#include <hip/hip_runtime.h>
#include <hip/hip_cooperative_groups.h>
#include <math.h>

namespace cg = cooperative_groups;

#define T_STEPS 64
#define B_      256
#define EMB_    1024
#define ACT_    6
#define STOCH_  64
#define HID_    512
#define FEAT_   512
#define STATE_  576
#define G3      1536
#define NBLK    256
#define NTHR    256
#define TM      64
#define TN      64
#define TK      32
#define XPAD    68   // padded row (float) for transposed LDS tiles; keeps 16B align, breaks conflicts

#define LOG2PI_ 1.8378770664093453

struct Params {
  const float *emb, *action, *reward, *eps;
  const float *Wih, *bih, *Whh, *bhh;
  const float *stW0,*stb0,*stW1,*stb1,*stW2,*stb2;
  const float *epW0,*epb0,*epW1,*epb1,*epW2,*epb2;
  const float *rpW0,*rpb0,*rpW1,*rpb1,*rpW2,*rpb2;
  float *h, *s, *gi, *gh, *pe0, *pe1, *pre_emb;
  float *pr0,*pr1,*pr2,*po0,*po1,*po2;
  float *states, *h1, *h2;
  double *acc;   // [0]=kl [1]=emb [2]=reward
  float *out;
};

__device__ __forceinline__ float elu_f(float x){ return x > 0.f ? x : expm1f(x); }
__device__ __forceinline__ float sigmoid_f(float x){ return 1.f/(1.f+expf(-x)); }
__device__ __forceinline__ float softplus_f(float x){ return x > 20.f ? x : log1pf(expf(x)); }

__device__ __forceinline__ double wave_sum(double v){
  #pragma unroll
  for (int o = 32; o > 0; o >>= 1) v += __shfl_down(v, o, 64);
  return v;
}

// C[64x64 tile] = act( [x0 | x1] @ W^T + bias ), W row-major [N][Ktot]
// X rows: r -> x0[r*ld0 + k] for k<K0, x1[r*ld1 + (k-K0)] for K0<=k<Ktot
__device__ void gemm_store(
    const float* __restrict__ x0, int ld0, int K0,
    const float* __restrict__ x1, int ld1,
    const float* __restrict__ W, const float* __restrict__ bias,
    int Ktot, int N,
    float* __restrict__ C, int ldc,
    int mt, int nt, int act,
    float (*Xs)[XPAD], float (*Ws)[XPAD])
{
  const int tid = threadIdx.x;
  const int tx = tid & 15, ty = tid >> 4;
  const int r0 = ty * 4, c0 = tx * 4;
  const int lr  = tid >> 2;         // 0..63 (row / out-col for loading)
  const int lk0 = (tid & 3) * 8;    // 0,8,16,24
  float acc[4][4] = {{0.f}};
  const int nkt = (Ktot + TK - 1) / TK;
  for (int kt = 0; kt < nkt; ++kt) {
    const int kb = kt * TK;
    __syncthreads();
    {
      const int row = mt * TM + lr;
      #pragma unroll
      for (int j = 0; j < 8; ++j) {
        const int k = kb + lk0 + j;
        float v = 0.f;
        if (k < K0)        v = x0[(long)row * ld0 + k];
        else if (k < Ktot) v = x1[(long)row * ld1 + (k - K0)];
        Xs[lk0 + j][lr] = v;
      }
      const int n = nt * TN + lr;
      #pragma unroll
      for (int j = 0; j < 8; ++j) {
        const int k = kb + lk0 + j;
        Ws[lk0 + j][lr] = (k < Ktot) ? W[(long)n * Ktot + k] : 0.f;
      }
    }
    __syncthreads();
    #pragma unroll
    for (int kk = 0; kk < TK; ++kk) {
      const float4 xv = *(const float4*)&Xs[kk][r0];
      const float4 wv = *(const float4*)&Ws[kk][c0];
      const float xa[4] = {xv.x, xv.y, xv.z, xv.w};
      const float wa[4] = {wv.x, wv.y, wv.z, wv.w};
      #pragma unroll
      for (int i = 0; i < 4; ++i)
        #pragma unroll
        for (int j = 0; j < 4; ++j)
          acc[i][j] += xa[i] * wa[j];
    }
  }
  #pragma unroll
  for (int i = 0; i < 4; ++i) {
    const int rg = mt * TM + r0 + i;
    #pragma unroll
    for (int j = 0; j < 4; ++j) {
      const int cg = nt * TN + c0 + j;
      float v = acc[i][j] + bias[cg];
      if (act == 1) v = elu_f(v);
      C[(long)rg * ldc + cg] = v;
    }
  }
}

// fused Gaussian NLL head: returns per-thread sum of 0.5*(tgt - (x@W^T+b))^2 over its tile outputs
__device__ double gemm_loss(
    const float* __restrict__ x0, int K0,
    const float* __restrict__ W, const float* __restrict__ bias,
    int N,
    const float* __restrict__ tgt, int ldt,
    int mt, int nt,
    float (*Xs)[XPAD], float (*Ws)[XPAD])
{
  const int tid = threadIdx.x;
  const int tx = tid & 15, ty = tid >> 4;
  const int r0 = ty * 4, c0 = tx * 4;
  const int lr  = tid >> 2;
  const int lk0 = (tid & 3) * 8;
  float acc[4][4] = {{0.f}};
  const int nkt = (K0 + TK - 1) / TK;
  for (int kt = 0; kt < nkt; ++kt) {
    const int kb = kt * TK;
    __syncthreads();
    {
      const int row = mt * TM + lr;
      #pragma unroll
      for (int j = 0; j < 8; ++j) {
        const int k = kb + lk0 + j;
        Xs[lk0 + j][lr] = (k < K0) ? x0[(long)row * K0 + k] : 0.f;
      }
      const int n = nt * TN + lr;
      #pragma unroll
      for (int j = 0; j < 8; ++j) {
        const int k = kb + lk0 + j;
        Ws[lk0 + j][lr] = (k < K0) ? W[(long)n * K0 + k] : 0.f;
      }
    }
    __syncthreads();
    #pragma unroll
    for (int kk = 0; kk < TK; ++kk) {
      const float4 xv = *(const float4*)&Xs[kk][r0];
      const float4 wv = *(const float4*)&Ws[kk][c0];
      const float xa[4] = {xv.x, xv.y, xv.z, xv.w};
      const float wa[4] = {wv.x, wv.y, wv.z, wv.w};
      #pragma unroll
      for (int i = 0; i < 4; ++i)
        #pragma unroll
        for (int j = 0; j < 4; ++j)
          acc[i][j] += xa[i] * wa[j];
    }
  }
  double ls = 0.0;
  #pragma unroll
  for (int i = 0; i < 4; ++i) {
    const int rg = mt * TM + r0 + i;
    #pragma unroll
    for (int j = 0; j < 4; ++j) {
      const int cg = nt * TN + c0 + j;
      const float mu = acc[i][j] + bias[cg];
      const float d = tgt[(long)rg * ldt + cg] - mu;
      ls += 0.5 * (double)d * (double)d;
    }
  }
  return ls;
}

__device__ __forceinline__ void kl_accum(const Params& p, int blk0, int nblks)
{
  const int tid = threadIdx.x;
  double lsum = 0.0;
  for (int i = (blockIdx.x - blk0) * NTHR + tid; i < B_ * STOCH_; i += nblks * NTHR) {
    const int b = i >> 6, j = i & 63;
    const float qmu  = p.po2[b * 128 + j];
    const float qstd = softplus_f(p.po2[b * 128 + 64 + j]) + 1e-4f;
    const float pmu  = p.pr2[b * 128 + j];
    const float pstd = softplus_f(p.pr2[b * 128 + 64 + j]) + 1e-4f;
    const float dm = qmu - pmu;
    lsum += (double)(logf(pstd / qstd) + (qstd * qstd + dm * dm) / (2.f * pstd * pstd) - 0.5f);
  }
  lsum = wave_sum(lsum);
  if ((tid & 63) == 0) atomicAdd(&p.acc[0], lsum);
}

__global__ void __launch_bounds__(NTHR) rssm_kernel(Params p)
{
  cg::grid_group grid = cg::this_grid();
  __shared__ float Xs[TK][XPAD];
  __shared__ float Ws[TK][XPAD];
  const int blk = blockIdx.x;
  const int tid = threadIdx.x;

  for (int t = 0; t < T_STEPS; ++t) {
    // ---- stage A: gi = [s,a]@Wih^T ; gh = h@Whh^T ; pe0 = elu([h,s]@epW0^T) ; KL(t-1)
    if (blk < 96) {
      gemm_store(p.s, STOCH_, STOCH_, p.action + (long)t * B_ * ACT_, ACT_,
                 p.Wih, p.bih, STOCH_ + ACT_, G3, p.gi, G3, blk / 24, blk % 24, 0, Xs, Ws);
    } else if (blk < 192) {
      const int ti = blk - 96;
      gemm_store(p.h, HID_, HID_, nullptr, 0,
                 p.Whh, p.bhh, HID_, G3, p.gh, G3, ti / 24, ti % 24, 0, Xs, Ws);
    } else if (blk < 224) {
      const int ti = blk - 192;
      gemm_store(p.h, HID_, HID_, p.s, STOCH_,
                 p.epW0, p.epb0, STATE_, FEAT_, p.pe0, FEAT_, ti / 8, ti % 8, 1, Xs, Ws);
    } else if (t > 0) {
      kl_accum(p, 224, 32);
    }
    grid.sync();
    // ---- stage B: GRU combine -> h (and states h-part) ; pe1 = elu(pe0@epW1^T)
    if (blk < 32) {
      gemm_store(p.pe0, FEAT_, FEAT_, nullptr, 0,
                 p.epW1, p.epb1, FEAT_, FEAT_, p.pe1, FEAT_, blk / 8, blk % 8, 1, Xs, Ws);
    } else {
      for (int i = (blk - 32) * NTHR + tid; i < B_ * HID_; i += 224 * NTHR) {
        const int b = i >> 9, j = i & 511;
        const float ir = p.gi[b * G3 + j],        hr = p.gh[b * G3 + j];
        const float iz = p.gi[b * G3 + 512 + j],  hz = p.gh[b * G3 + 512 + j];
        const float in_= p.gi[b * G3 + 1024 + j], hn = p.gh[b * G3 + 1024 + j];
        const float r = sigmoid_f(ir + hr);
        const float z = sigmoid_f(iz + hz);
        const float n = tanhf(in_ + r * hn);
        const float hv = (1.f - z) * n + z * p.h[b * HID_ + j];
        p.h[b * HID_ + j] = hv;
        p.states[((long)t * B_ + b) * STATE_ + j] = hv;
      }
    }
    grid.sync();
    // ---- stage C: pre_emb = pe1@epW2^T ; po0 = elu([h_new, emb_prev]@stW0^T)
    {
      const float* eprev = p.emb + (long)(t > 0 ? t - 1 : 0) * B_ * EMB_;
      if (blk < 64) {
        gemm_store(p.pe1, FEAT_, FEAT_, nullptr, 0,
                   p.epW2, p.epb2, FEAT_, EMB_, p.pre_emb, EMB_, blk / 16, blk % 16, 0, Xs, Ws);
      } else if (blk < 96) {
        const int ti = blk - 64;
        gemm_store(p.h, HID_, HID_, eprev, EMB_,
                   p.stW0, p.stb0, G3, FEAT_, p.po0, FEAT_, ti / 8, ti % 8, 1, Xs, Ws);
      }
    }
    grid.sync();
    // ---- stage D: pr0 = elu([h_new, pre_emb]@stW0^T) ; po1 = elu(po0@stW1^T)
    if (blk < 32) {
      gemm_store(p.h, HID_, HID_, p.pre_emb, EMB_,
                 p.stW0, p.stb0, G3, FEAT_, p.pr0, FEAT_, blk / 8, blk % 8, 1, Xs, Ws);
    } else if (blk < 64) {
      const int ti = blk - 32;
      gemm_store(p.po0, FEAT_, FEAT_, nullptr, 0,
                 p.stW1, p.stb1, FEAT_, FEAT_, p.po1, FEAT_, ti / 8, ti % 8, 1, Xs, Ws);
    }
    grid.sync();
    // ---- stage E: pr1 = elu(pr0@stW1^T) ; po2 = po1@stW2^T
    if (blk < 32) {
      gemm_store(p.pr0, FEAT_, FEAT_, nullptr, 0,
                 p.stW1, p.stb1, FEAT_, FEAT_, p.pr1, FEAT_, blk / 8, blk % 8, 1, Xs, Ws);
    } else if (blk < 40) {
      const int ti = blk - 32;
      gemm_store(p.po1, FEAT_, FEAT_, nullptr, 0,
                 p.stW2, p.stb2, FEAT_, 128, p.po2, 128, ti / 2, ti % 2, 0, Xs, Ws);
    }
    grid.sync();
    // ---- stage F: pr2 = pr1@stW2^T ; sample s_new = qmu + qstd*eps (and states s-part)
    if (blk < 8) {
      gemm_store(p.pr1, FEAT_, FEAT_, nullptr, 0,
                 p.stW2, p.stb2, FEAT_, 128, p.pr2, 128, blk / 2, blk % 2, 0, Xs, Ws);
    } else {
      const int base = (blk - 8) * NTHR + tid;
      if (base < B_ * STOCH_) {
        const int b = base >> 6, j = base & 63;
        const float qmu  = p.po2[b * 128 + j];
        const float qstd = softplus_f(p.po2[b * 128 + 64 + j]) + 1e-4f;
        const float sv = qmu + qstd * p.eps[((long)t * B_ + b) * STOCH_ + j];
        p.s[b * STOCH_ + j] = sv;
        p.states[((long)t * B_ + b) * STATE_ + HID_ + j] = sv;
      }
    }
    grid.sync();
  }

  // final KL (t = 63)
  kl_accum(p, 0, NBLK);
  grid.sync();

  // ---- emb reconstruction head over 4 chunks of 4096 rows
  for (int ch = 0; ch < 4; ++ch) {
    const float* xs = p.states + (long)ch * 4096 * STATE_;
    for (int ti = blk; ti < 64 * 8; ti += NBLK)
      gemm_store(xs, STATE_, STATE_, nullptr, 0,
                 p.epW0, p.epb0, STATE_, FEAT_, p.h1, FEAT_, ti / 8, ti % 8, 1, Xs, Ws);
    grid.sync();
    for (int ti = blk; ti < 64 * 8; ti += NBLK)
      gemm_store(p.h1, FEAT_, FEAT_, nullptr, 0,
                 p.epW1, p.epb1, FEAT_, FEAT_, p.h2, FEAT_, ti / 8, ti % 8, 1, Xs, Ws);
    grid.sync();
    {
      double lsum = 0.0;
      const float* tgt = p.emb + (long)ch * 4096 * EMB_;
      for (int ti = blk; ti < 64 * 16; ti += NBLK)
        lsum += gemm_loss(p.h2, FEAT_, p.epW2, p.epb2, EMB_, tgt, EMB_, ti / 16, ti % 16, Xs, Ws);
      lsum = wave_sum(lsum);
      if ((tid & 63) == 0) atomicAdd(&p.acc[1], lsum);
    }
    grid.sync();
  }

  // ---- reward head over 4 chunks
  for (int ch = 0; ch < 4; ++ch) {
    const float* xs = p.states + (long)ch * 4096 * STATE_;
    for (int ti = blk; ti < 64 * 8; ti += NBLK)
      gemm_store(xs, STATE_, STATE_, nullptr, 0,
                 p.rpW0, p.rpb0, STATE_, FEAT_, p.h1, FEAT_, ti / 8, ti % 8, 1, Xs, Ws);
    grid.sync();
    for (int ti = blk; ti < 64 * 8; ti += NBLK)
      gemm_store(p.h1, FEAT_, FEAT_, nullptr, 0,
                 p.rpW1, p.rpb1, FEAT_, FEAT_, p.h2, FEAT_, ti / 8, ti % 8, 1, Xs, Ws);
    grid.sync();
    {
      double lsum = 0.0;
      const int wave = (blk * NTHR + tid) >> 6;
      const int lane = tid & 63;
      for (int row = wave; row < 4096; row += (NBLK * NTHR) >> 6) {
        float part = 0.f;
        for (int k = lane; k < FEAT_; k += 64)
          part += p.h2[(long)row * FEAT_ + k] * p.rpW2[k];
        #pragma unroll
        for (int o = 32; o > 0; o >>= 1) part += __shfl_down(part, o, 64);
        if (lane == 0) {
          const float mu = part + p.rpb2[0];
          const float d = p.reward[(long)ch * 4096 + row] - mu;
          lsum += 0.5 * (double)d * (double)d;
        }
      }
      lsum = wave_sum(lsum);
      if ((tid & 63) == 0) atomicAdd(&p.acc[2], lsum);
    }
    grid.sync();
  }

  if (blk == 0 && tid == 0) {
    const double k = atomicAdd(&p.acc[0], 0.0);
    const double e = atomicAdd(&p.acc[1], 0.0);
    const double r = atomicAdd(&p.acc[2], 0.0);
    // constants: emb: EMB*0.5*log(2pi) per row ; reward: 0.5*log(2pi) per row
    const double tot = (k + e + r) / (double)(T_STEPS * B_)
                     + 512.0 * LOG2PI_ + 0.5 * LOG2PI_;
    p.out[0] = (float)tot;
  }
}

extern "C" void kernel_launch(void* const* d_in, const int* in_sizes, int n_in,
                              void* d_out, int out_size, void* d_ws, size_t ws_size,
                              hipStream_t stream) {
  Params p;
  p.emb    = (const float*)d_in[0];
  p.action = (const float*)d_in[1];
  p.reward = (const float*)d_in[2];
  p.eps    = (const float*)d_in[3];
  p.Wih  = (const float*)d_in[4];  p.bih  = (const float*)d_in[5];
  p.Whh  = (const float*)d_in[6];  p.bhh  = (const float*)d_in[7];
  p.stW0 = (const float*)d_in[8];  p.stb0 = (const float*)d_in[9];
  p.stW1 = (const float*)d_in[10]; p.stb1 = (const float*)d_in[11];
  p.stW2 = (const float*)d_in[12]; p.stb2 = (const float*)d_in[13];
  p.epW0 = (const float*)d_in[14]; p.epb0 = (const float*)d_in[15];
  p.epW1 = (const float*)d_in[16]; p.epb1 = (const float*)d_in[17];
  p.epW2 = (const float*)d_in[18]; p.epb2 = (const float*)d_in[19];
  p.rpW0 = (const float*)d_in[20]; p.rpb0 = (const float*)d_in[21];
  p.rpW1 = (const float*)d_in[22]; p.rpb1 = (const float*)d_in[23];
  p.rpW2 = (const float*)d_in[24]; p.rpb2 = (const float*)d_in[25];

  p.acc = (double*)d_ws;
  float* f = (float*)((char*)d_ws + 256);
  p.h = f;        f += 256 * 512;
  p.s = f;        f += 256 * 64;
  p.gi = f;       f += 256 * 1536;
  p.gh = f;       f += 256 * 1536;
  p.pe0 = f;      f += 256 * 512;
  p.pe1 = f;      f += 256 * 512;
  p.pre_emb = f;  f += 256 * 1024;
  p.pr0 = f;      f += 256 * 512;
  p.pr1 = f;      f += 256 * 512;
  p.pr2 = f;      f += 256 * 128;
  p.po0 = f;      f += 256 * 512;
  p.po1 = f;      f += 256 * 512;
  p.po2 = f;      f += 256 * 128;
  p.states = f;   f += (long)16384 * 576;
  p.h1 = f;       f += (long)4096 * 512;
  p.h2 = f;       f += (long)4096 * 512;
  p.out = (float*)d_out;

  // zero loss accumulators + h0/s0 carries (h and s are contiguous after the 256B acc header)
  hipMemsetAsync(d_ws, 0, 256 + (size_t)(256 * 512 + 256 * 64) * sizeof(float), stream);

  void* args[] = { &p };
  hipLaunchCooperativeKernel((void*)rssm_kernel, dim3(NBLK), dim3(NTHR), args, 0, stream);
}